// Round 4
// baseline (8601.617 us; speedup 1.0000x reference)
//
#include <hip/hip_runtime.h>
#include <hip/hip_bf16.h>
#include <math.h>

#define NN    10000
#define FIN   128
#define NHID  128
#define PIF   3.14159265358979323846f

__device__ __forceinline__ float lrelu(float x) { return x > 0.f ? x : 0.2f * x; }

// ---------------- filters: phi(8l), psi(l/4), psi(l/2) per node ----------------
__global__ void k_filters(const float* __restrict__ lamb, float* __restrict__ filt) {
    int i = blockIdx.x * blockDim.x + threadIdx.x;
    if (i >= NN) return;
    float l = lamb[i];
    float a = 8.f * l; if (a == 0.f) a = 1e-7f;
    float ya = 2.f * PIF * a;
    filt[i] = sinf(ya) / ya;
    float b = l * 0.25f; if (b == 0.f) b = 1e-8f;
    filt[NN + i] = sinf(b) / (PIF * b) * (1.f - cosf(b));
    float c = l * 0.5f; if (c == 0.f) c = 1e-8f;
    filt[2 * NN + i] = sinf(c) / (PIF * c) * (1.f - cosf(c));
}

// ---------------- h = x @ W1 + b1 ----------------
__global__ void k_xw1(const float* __restrict__ x, const float* __restrict__ W1,
                      const float* __restrict__ b1, float* __restrict__ h) {
    int t = blockIdx.x * blockDim.x + threadIdx.x;
    if (t >= NN * NHID) return;
    int n = t >> 7, j = t & 127;
    const float* xr = x + (size_t)n * FIN;
    float acc = b1[j];
    for (int k = 0; k < FIN; k++) acc += xr[k] * W1[k * NHID + j];
    h[t] = acc;
}

// ---------------- C = A^T @ X ; A is KxM fp32 (V), X is KxNc fp32 ----------------
__global__ __launch_bounds__(256) void k_gemm_tn(
    const float* __restrict__ A, const float* __restrict__ X, float* __restrict__ C,
    int M, int K, int lda, int ncols, int ldc)
{
    __shared__ float As[16][68];
    __shared__ float Bs[16][68];
    int tx = threadIdx.x, ty = threadIdx.y;
    int tid = ty * 16 + tx;
    int i0 = blockIdx.y * 64, j0 = blockIdx.x * 64;
    int lk = tid >> 4, lc4 = (tid & 15) * 4;
    float acc[4][4] = {{0.f}};
    for (int k0 = 0; k0 < K; k0 += 16) {
        int gi = i0 + lc4;
        const float* ap = A + (size_t)(k0 + lk) * lda + gi;
        float4 av;
        if (gi + 3 < M) {
            av = *(const float4*)ap;
        } else {
            av.x = (gi + 0 < M) ? ap[0] : 0.f;
            av.y = (gi + 1 < M) ? ap[1] : 0.f;
            av.z = (gi + 2 < M) ? ap[2] : 0.f;
            av.w = (gi + 3 < M) ? ap[3] : 0.f;
        }
        *(float4*)&As[lk][lc4] = av;
        const float* xp = X + (size_t)(k0 + lk) * ncols + j0 + lc4;
        *(float4*)&Bs[lk][lc4] = *(const float4*)xp;
        __syncthreads();
#pragma unroll
        for (int kk = 0; kk < 16; kk++) {
            float4 a4 = *(float4*)&As[kk][ty * 4];
            float4 b4 = *(float4*)&Bs[kk][tx * 4];
            float avr[4] = {a4.x, a4.y, a4.z, a4.w};
            float bvr[4] = {b4.x, b4.y, b4.z, b4.w};
#pragma unroll
            for (int r = 0; r < 4; r++)
#pragma unroll
                for (int c = 0; c < 4; c++) acc[r][c] += avr[r] * bvr[c];
        }
        __syncthreads();
    }
#pragma unroll
    for (int r = 0; r < 4; r++) {
        int i = i0 + ty * 4 + r;
        if (i < M) {
            float4 o = make_float4(acc[r][0], acc[r][1], acc[r][2], acc[r][3]);
            *(float4*)&C[(size_t)i * ldc + j0 + tx * 4] = o;
        }
    }
}

// ---------------- C = A @ X ; A is MxK fp32 (V), X is KxNc fp32 ----------------
__global__ __launch_bounds__(256) void k_gemm_nn(
    const float* __restrict__ A, const float* __restrict__ X, float* __restrict__ C,
    int M, int K, int lda, int ncols, int ldc)
{
    __shared__ float As[16][68];
    __shared__ float Bs[16][68];
    int tx = threadIdx.x, ty = threadIdx.y;
    int tid = ty * 16 + tx;
    int i0 = blockIdx.y * 64, j0 = blockIdx.x * 64;
    int lk = tid >> 4, lc4 = (tid & 15) * 4;
    int ii = tid >> 2, kq = (tid & 3) * 4;
    float acc[4][4] = {{0.f}};
    for (int k0 = 0; k0 < K; k0 += 16) {
        float4 a = make_float4(0.f, 0.f, 0.f, 0.f);
        if (i0 + ii < M) {
            const float* ap = A + (size_t)(i0 + ii) * lda + k0 + kq;
            a = *(const float4*)ap;
        }
        As[kq + 0][ii] = a.x; As[kq + 1][ii] = a.y; As[kq + 2][ii] = a.z; As[kq + 3][ii] = a.w;
        const float* xp = X + (size_t)(k0 + lk) * ncols + j0 + lc4;
        *(float4*)&Bs[lk][lc4] = *(const float4*)xp;
        __syncthreads();
#pragma unroll
        for (int kk = 0; kk < 16; kk++) {
            float4 a4 = *(float4*)&As[kk][ty * 4];
            float4 b4 = *(float4*)&Bs[kk][tx * 4];
            float avr[4] = {a4.x, a4.y, a4.z, a4.w};
            float bvr[4] = {b4.x, b4.y, b4.z, b4.w};
#pragma unroll
            for (int r = 0; r < 4; r++)
#pragma unroll
                for (int c = 0; c < 4; c++) acc[r][c] += avr[r] * bvr[c];
        }
        __syncthreads();
    }
#pragma unroll
    for (int r = 0; r < 4; r++) {
        int i = i0 + ty * 4 + r;
        if (i < M) {
            float4 o = make_float4(acc[r][0], acc[r][1], acc[r][2], acc[r][3]);
            *(float4*)&C[(size_t)i * ldc + j0 + tx * 4] = o;
        }
    }
}

// ---------------- B[n, f*G*128 + g*128 + c] = filt[f][n] * T[n, g*128+c] ----------------
__global__ void k_expand(const float* __restrict__ T, float* __restrict__ B,
                         const float* __restrict__ filt, int G, int nf) {
    int t = blockIdx.x * blockDim.x + threadIdx.x;
    int tc = G * 128;
    int total = NN * tc;
    if (t >= total) return;
    int n = t / tc;
    int rem = t - n * tc;
    float v = T[t];
    size_t ob = (size_t)n * (nf * tc);
    for (int f = 0; f < nf; f++) B[ob + f * tc + rem] = filt[f * NN + n] * v;
}

// ---------------- abs block copy: Xa[n,0:ncols] = |Y[n, soff:soff+ncols]| ----------------
__global__ void k_abscopy(const float* __restrict__ src, int sld, int soff,
                          float* __restrict__ dst, int dld, int ncols) {
    int t = blockIdx.x * blockDim.x + threadIdx.x;
    int total = NN * ncols;
    if (t >= total) return;
    int n = t / ncols;
    int c = t - n * ncols;
    dst[(size_t)n * dld + c] = fabsf(src[(size_t)n * sld + soff + c]);
}

// ---------------- r2[n,0:32] += Y[n, c0:c0+C] @ W[0:C, 0:32] ----------------
__global__ void k_y2h2(const float* __restrict__ Y, int ldy, int c0, int C,
                       const float* __restrict__ Wp, float* __restrict__ r2) {
    int t = blockIdx.x * blockDim.x + threadIdx.x;
    if (t >= NN * 32) return;
    int n = t >> 5, j = t & 31;
    const float* yr = Y + (size_t)n * ldy + c0;
    float acc = 0.f;
    for (int k = 0; k < C; k++) acc += yr[k] * Wp[k * 32 + j];
    r2[t] += acc;
}

__global__ void k_zero_f(float* p, int n) {
    int i = blockIdx.x * blockDim.x + threadIdx.x;
    if (i < n) p[i] = 0.f;
}

// ---------------- CSR build ----------------
__global__ void k_zero_int(int* p, int n) {
    int i = blockIdx.x * blockDim.x + threadIdx.x;
    if (i < n) p[i] = 0;
}
__global__ void k_count(const int* __restrict__ dst, int* __restrict__ deg, int E) {
    int e = blockIdx.x * blockDim.x + threadIdx.x;
    if (e < E) atomicAdd(&deg[dst[e]], 1);
}
__global__ __launch_bounds__(1024) void k_scan(const int* __restrict__ deg,
                                               int* __restrict__ rowp, int* __restrict__ cur, int E) {
    __shared__ int s[1024];
    int t = threadIdx.x;
    int base = t * 10;
    int sum = 0;
    for (int i = 0; i < 10; i++) { int idx = base + i; if (idx < NN) sum += deg[idx]; }
    s[t] = sum; __syncthreads();
    for (int off = 1; off < 1024; off <<= 1) {
        int v = (t >= off) ? s[t - off] : 0;
        __syncthreads();
        s[t] += v;
        __syncthreads();
    }
    int run = (t > 0) ? s[t - 1] : 0;
    for (int i = 0; i < 10; i++) {
        int idx = base + i;
        if (idx < NN) { rowp[idx] = run; cur[idx] = run; run += deg[idx]; }
    }
    if (t == 0) rowp[NN] = E;
}
__global__ void k_fill(const int* __restrict__ src, const int* __restrict__ dst,
                       int* __restrict__ cur, int* __restrict__ csr, int E) {
    int e = blockIdx.x * blockDim.x + threadIdx.x;
    if (e < E) {
        int d = dst[e];
        int p = atomicAdd(&cur[d], 1);
        csr[p] = src[e];
    }
}

// ---------------- h2[n,j] = sum over in-edges r2[src,j]  (32 feat) ----------------
__global__ void k_agg32(const float* __restrict__ r2, const int* __restrict__ rowp,
                        const int* __restrict__ csr, float* __restrict__ h2) {
    int t = blockIdx.x * blockDim.x + threadIdx.x;
    if (t >= NN * 32) return;
    int n = t >> 5, j = t & 31;
    int s0 = rowp[n], s1 = rowp[n + 1];
    float a = 0.f;
    for (int e = s0; e < s1; e++) a += r2[(size_t)csr[e] * 32 + j];
    h2[t] = a;
}

// ---------------- attention logits per node/head ----------------
__global__ void k_att(const float* __restrict__ h2, const float* __restrict__ att_s,
                      const float* __restrict__ att_d, float* __restrict__ asrc,
                      float* __restrict__ adst) {
    int t = blockIdx.x * blockDim.x + threadIdx.x;
    if (t >= NN * 2) return;
    int n = t >> 1, hh = t & 1;
    const float* hr = h2 + (size_t)n * 32 + hh * 16;
    float s = 0.f, d = 0.f;
    for (int c = 0; c < 16; c++) {
        float v = hr[c];
        s += v * att_s[hh * 16 + c];
        d += v * att_d[hh * 16 + c];
    }
    asrc[t] = s; adst[t] = d;
}

// ---------------- GAT softmax-aggregate, one 64-thread block per dst ----------------
__global__ __launch_bounds__(64) void k_gat(const float* __restrict__ h2,
                                            const float* __restrict__ asrc,
                                            const float* __restrict__ adst,
                                            const int* __restrict__ rowp,
                                            const int* __restrict__ csr,
                                            const float* __restrict__ bias,
                                            float* __restrict__ gout) {
    int d = blockIdx.x, lane = threadIdx.x;
    int s0 = rowp[d], s1 = rowp[d + 1];
    __shared__ float sm[2], sden[2];
    int hh = lane >> 5;
    float adh = adst[d * 2 + hh];
    float eself = lrelu(asrc[d * 2 + hh] + adh);
    float m = eself;
    for (int j = s0 + (lane & 31); j < s1; j += 32) {
        int s = csr[j];
        m = fmaxf(m, lrelu(asrc[s * 2 + hh] + adh));
    }
    for (int off = 16; off; off >>= 1) m = fmaxf(m, __shfl_xor(m, off, 32));
    float den = ((lane & 31) == 0) ? expf(eself - m) : 0.f;
    for (int j = s0 + (lane & 31); j < s1; j += 32) {
        int s = csr[j];
        den += expf(lrelu(asrc[s * 2 + hh] + adh) - m);
    }
    for (int off = 16; off; off >>= 1) den += __shfl_xor(den, off, 32);
    if ((lane & 31) == 0) { sm[hh] = m; sden[hh] = den; }
    __syncthreads();
    int f = lane & 31;
    int h3 = f >> 4;
    float mh = sm[h3], dh = sden[h3];
    float ad3 = adst[d * 2 + h3];
    float acc = 0.f;
    for (int j = s0 + (lane >> 5); j < s1; j += 2) {
        int s = csr[j];
        float e = lrelu(asrc[s * 2 + h3] + ad3);
        acc += expf(e - mh) * h2[(size_t)s * 32 + f];
    }
    if ((lane >> 5) == 0) {
        float es = lrelu(asrc[d * 2 + h3] + ad3);
        acc += expf(es - mh) * h2[(size_t)d * 32 + f];
    }
    acc += __shfl_down(acc, 32, 64);
    if (lane < 32) gout[(size_t)d * 32 + f] = acc / dh + bias[f];
}

// ---------------- g = elu(gout) @ mlp_W + mlp_b ----------------
__global__ void k_mlp(const float* __restrict__ gout, const float* __restrict__ mw,
                      const float* __restrict__ mb, float* __restrict__ g) {
    int t = blockIdx.x * blockDim.x + threadIdx.x;
    if (t >= NN * 16) return;
    int n = t >> 4, j = t & 15;
    const float* gr = gout + (size_t)n * 32;
    float acc = mb[j];
    for (int k = 0; k < 32; k++) {
        float v = gr[k];
        v = v > 0.f ? v : expm1f(v);
        acc += v * mw[k * 16 + j];
    }
    g[t] = acc;
}

// ---------------- final edge-sum + log_softmax (fp32 output) ----------------
__global__ __launch_bounds__(64) void k_final(const float* __restrict__ g,
                                              const int* __restrict__ rowp,
                                              const int* __restrict__ csr,
                                              float* __restrict__ out) {
    int d = blockIdx.x, lane = threadIdx.x;
    int s0 = rowp[d], s1 = rowp[d + 1];
    int f = lane & 15, grp = lane >> 4;
    float acc = 0.f;
    for (int j = s0 + grp; j < s1; j += 4) acc += g[(size_t)csr[j] * 16 + f];
    acc += __shfl_xor(acc, 16, 64);
    acc += __shfl_xor(acc, 32, 64);
    float mx = acc;
    for (int off = 8; off; off >>= 1) mx = fmaxf(mx, __shfl_xor(mx, off, 16));
    float ex = expf(acc - mx);
    float se = ex;
    for (int off = 8; off; off >>= 1) se += __shfl_xor(se, off, 16);
    if (lane < 16) out[(size_t)d * 16 + f] = acc - mx - logf(se);
}

extern "C" void kernel_launch(void* const* d_in, const int* in_sizes, int n_in,
                              void* d_out, int out_size, void* d_ws, size_t ws_size,
                              hipStream_t stream) {
    (void)n_in; (void)out_size; (void)ws_size;
    const float* x       = (const float*)d_in[0];
    const int*   ei      = (const int*)d_in[1];
    const float* lamb    = (const float*)d_in[2];
    const float* V       = (const float*)d_in[3];
    const float* W1      = (const float*)d_in[4];
    const float* b1      = (const float*)d_in[5];
    const float* gat_W   = (const float*)d_in[6];
    const float* att_src = (const float*)d_in[7];
    const float* att_dst = (const float*)d_in[8];
    const float* gat_b   = (const float*)d_in[9];
    const float* mlp_W   = (const float*)d_in[10];
    const float* mlp_b   = (const float*)d_in[11];
    float* out = (float*)d_out;
    const int E = in_sizes[1] / 2;
    const int* e_src = ei;
    const int* e_dst = ei + E;

    char* w = (char*)d_ws;
    auto alloc = [&](size_t bytes) { void* p = (void*)w; w += (bytes + 255) & ~(size_t)255; return p; };
    float* h    = (float*)alloc((size_t)NN * 128 * 4);
    float* TY   = (float*)alloc((size_t)NN * 768 * 4);  // T (<=512 cols) then Y (<=768 cols)
    float* Bb   = (float*)alloc((size_t)NN * 768 * 4);
    float* Xa   = (float*)alloc((size_t)NN * 512 * 4);
    float* r2   = (float*)alloc((size_t)NN * 32 * 4);
    float* h2   = (float*)alloc((size_t)NN * 32 * 4);
    float* asrc = (float*)alloc((size_t)NN * 2 * 4);
    float* adst = (float*)alloc((size_t)NN * 2 * 4);
    float* gout = (float*)alloc((size_t)NN * 32 * 4);
    float* g    = (float*)alloc((size_t)NN * 16 * 4);
    float* filt = (float*)alloc((size_t)3 * NN * 4);
    int* deg    = (int*)alloc((size_t)NN * 4);
    int* rowp   = (int*)alloc((size_t)(NN + 1) * 4);
    int* cur    = (int*)alloc((size_t)NN * 4);
    int* csr    = (int*)alloc((size_t)E * 4);

    dim3 tb(16, 16, 1);
    int rowTiles = (NN + 63) / 64;

    // CSR build
    k_zero_int<<<(NN + 255) / 256, 256, 0, stream>>>(deg, NN);
    k_count<<<(E + 255) / 256, 256, 0, stream>>>(e_dst, deg, E);
    k_scan<<<1, 1024, 0, stream>>>(deg, rowp, cur, E);
    k_fill<<<(E + 255) / 256, 256, 0, stream>>>(e_src, e_dst, cur, csr, E);

    k_filters<<<(NN + 255) / 256, 256, 0, stream>>>(lamb, filt);
    k_xw1<<<(NN * NHID + 255) / 256, 256, 0, stream>>>(x, W1, b1, h);
    k_zero_f<<<(NN * 32 + 255) / 256, 256, 0, stream>>>(r2, NN * 32);

    // ---- Level 0 ----
    k_gemm_tn<<<dim3(128 / 64, rowTiles), tb, 0, stream>>>(V, h, TY, NN, NN, NN, 128, 128);
    k_expand<<<((NN * 128) + 255) / 256, 256, 0, stream>>>(TY, Bb, filt, 1, 3);
    k_gemm_nn<<<dim3(384 / 64, rowTiles), tb, 0, stream>>>(V, Bb, TY, NN, NN, NN, 384, 384);
    k_y2h2<<<((NN * 32) + 255) / 256, 256, 0, stream>>>(TY, 384, 0, 128, gat_W + 0 * 32, r2);
    k_abscopy<<<((NN * 256) + 255) / 256, 256, 0, stream>>>(TY, 384, 128, Xa, 256, 256);

    // ---- Level 1 ----
    k_gemm_tn<<<dim3(256 / 64, rowTiles), tb, 0, stream>>>(V, Xa, TY, NN, NN, NN, 256, 256);
    k_expand<<<((NN * 256) + 255) / 256, 256, 0, stream>>>(TY, Bb, filt, 2, 3);
    k_gemm_nn<<<dim3(768 / 64, rowTiles), tb, 0, stream>>>(V, Bb, TY, NN, NN, NN, 768, 768);
    k_y2h2<<<((NN * 32) + 255) / 256, 256, 0, stream>>>(TY, 768, 0, 256, gat_W + 128 * 32, r2);
    k_abscopy<<<((NN * 512) + 255) / 256, 256, 0, stream>>>(TY, 768, 256, Xa, 512, 512);

    // ---- Level 2 (phi-children only) ----
    k_gemm_tn<<<dim3(512 / 64, rowTiles), tb, 0, stream>>>(V, Xa, TY, NN, NN, NN, 512, 512);
    k_expand<<<((NN * 512) + 255) / 256, 256, 0, stream>>>(TY, Bb, filt, 4, 1);
    k_gemm_nn<<<dim3(512 / 64, rowTiles), tb, 0, stream>>>(V, Bb, TY, NN, NN, NN, 512, 512);
    // Y groups [u0,u1,u2,u3]=[z1(y1),z1(y2),z2(y1),z2(y2)] -> rep blocks {3,5,4,6}
    k_y2h2<<<((NN * 32) + 255) / 256, 256, 0, stream>>>(TY, 512, 0,   128, gat_W + 384 * 32, r2);
    k_y2h2<<<((NN * 32) + 255) / 256, 256, 0, stream>>>(TY, 512, 128, 128, gat_W + 640 * 32, r2);
    k_y2h2<<<((NN * 32) + 255) / 256, 256, 0, stream>>>(TY, 512, 256, 128, gat_W + 512 * 32, r2);
    k_y2h2<<<((NN * 32) + 255) / 256, 256, 0, stream>>>(TY, 512, 384, 128, gat_W + 768 * 32, r2);

    // ---- graph ops ----
    k_agg32<<<((NN * 32) + 255) / 256, 256, 0, stream>>>(r2, rowp, csr, h2);
    k_att<<<((NN * 2) + 255) / 256, 256, 0, stream>>>(h2, att_src, att_dst, asrc, adst);
    k_gat<<<NN, 64, 0, stream>>>(h2, asrc, adst, rowp, csr, gat_b, gout);
    k_mlp<<<((NN * 16) + 255) / 256, 256, 0, stream>>>(gout, mlp_W, mlp_b, g);
    k_final<<<NN, 64, 0, stream>>>(g, rowp, csr, out);
}